// Round 5
// baseline (22740.755 us; speedup 1.0000x reference)
//
#include <hip/hip_runtime.h>

// DecoderRNN: 3-layer LSTM (H=1024) + fc, B=256, 128 steps, constant input.
// bf16 MFMA 16x16x32; gate-interleaved weight columns so the LSTM cell update
// is lane-local in the matmul epilogue; pipelined launches
// {L0(i), L1(i-1), L2(i-2), fc(i-3)} with parity-double-buffered h state.
// THIS ROUND: barrier-free, LDS-free direct global->register MFMA streaming,
// depth-8 named-buffer prefetch (48 loads in flight per wave, zero syncs).

#define DEVINL static __device__ __forceinline__

typedef __bf16 bf16x8 __attribute__((ext_vector_type(8)));
typedef float f32x4 __attribute__((ext_vector_type(4)));
typedef unsigned short u16;
typedef unsigned int u32;

DEVINL u16 f2bf(float f) {
  u32 u = __builtin_bit_cast(u32, f);
  u += 0x7fffu + ((u >> 16) & 1u);  // RNE
  return (u16)(u >> 16);
}
DEVINL float bf2f(u16 h) {
  u32 u = (u32)h << 16;
  return __builtin_bit_cast(float, u);
}
DEVINL float sigm(float x) { return 1.0f / (1.0f + __expf(-x)); }
DEVINL float tanhfast(float x) { return 1.0f - 2.0f / (1.0f + __expf(2.0f * x)); }
DEVINL bf16x8 bc(uint4 v) { return __builtin_bit_cast(bf16x8, v); }

// permuted column index -> original gate column: P = grp*64 + g*16 + jj
// maps hidden unit j = grp*16+jj, gate g  ->  orig n = g*1024 + j
DEVINL int permcol(int P) {
  int grp = P >> 6, g = (P >> 4) & 3, jj = P & 15;
  return g * 1024 + grp * 16 + jj;
}

struct Params {
  const float* fc_b;
  const float* inh_b;
  const float* inc_b;
  const u16 *WT0, *WT1, *WT2, *WT00, *FCW, *WIH, *WIC, *FRB;
  u16* HB;   // h state bf16: [layer][parity][256][1024]
  u16* G0P;  // precomputed layer0 input gates, bf16 [256][4096]
  float *G0B, *B1P, *B2P, *CC;  // CC: c state fp32 [layer][256][1024]
  float* out;
};

#define MODE_L0 0
#define MODE_L 1
#define MODE_FC 2
#define MODE_G0 3
#define MODE_H 4
#define MODE_C 5

// Wave-autonomous 32(M) x 64(N) output tile, no LDS, no barriers.
// A-frag (16x32): lane holds A[mw + (l&15)][k + (l>>4)*8 .. +8) -> 16B load,
//   16 rows x 64B contiguous per instruction. Second frag at +16 rows.
// B-frag: WT is [col][k]; lane holds WT[n0 + (l&15)][k + (l>>4)*8 ..) -> same.
// Depth-8 half-K (32) pipeline with named buffers (static indexing only).
template <int MODE>
DEVINL void mm_body(const u16* A0, const u16* A1, int sA, int kSplit, int K,
                    const u16* Wt, int m0, int bn, int t, const u16* Gfull,
                    const float* biasP, float* Cst, u16* Hout, float* outp) {
  const int tid = threadIdx.x;
  const int l = tid & 63;
  const int w = tid >> 6;  // wave -> M sub-tile
  const int jj = l & 15;
  const int kg = (l >> 4) & 3;
  const int mw = m0 + w * 32;

  f32x4 acc[2][4];
#pragma unroll
  for (int m = 0; m < 2; ++m)
#pragma unroll
    for (int g = 0; g < 4; ++g) acc[m][g] = (f32x4){0.f, 0.f, 0.f, 0.f};

  // per-lane base pointers (element units)
  const size_t aoff = (size_t)(mw + jj) * sA + kg * 8;
  const u16* ApA = A0 + aoff;
  const u16* ApB = A1 ? (A1 + aoff) : (A0 + aoff);
  const u16* Bp = Wt + (size_t)(bn * 64 + jj) * K + kg * 8;
  const size_t sK16 = (size_t)16 * K;
  const size_t sA16 = (size_t)16 * sA;

#define DECL_SLOT(S) uint4 a0##S, a1##S, b0##S, b1##S, b2##S, b3##S;
  DECL_SLOT(0) DECL_SLOT(1) DECL_SLOT(2) DECL_SLOT(3)
  DECL_SLOT(4) DECL_SLOT(5) DECL_SLOT(6) DECL_SLOT(7)

#define ISSUE(S, II)                                                   \
  {                                                                    \
    int ko_ = (II)*32;                                                 \
    const u16* Ap_ = (ko_ < kSplit) ? (ApA + ko_) : (ApB + (ko_ - kSplit)); \
    a0##S = *(const uint4*)Ap_;                                        \
    a1##S = *(const uint4*)(Ap_ + sA16);                               \
    const u16* Bq_ = Bp + ko_;                                         \
    b0##S = *(const uint4*)Bq_;                                        \
    b1##S = *(const uint4*)(Bq_ + sK16);                               \
    b2##S = *(const uint4*)(Bq_ + 2 * sK16);                           \
    b3##S = *(const uint4*)(Bq_ + 3 * sK16);                           \
  }

#define COMPUTE(S)                                                                 \
  {                                                                                \
    bf16x8 fa0 = bc(a0##S), fa1 = bc(a1##S);                                       \
    bf16x8 fb0 = bc(b0##S), fb1 = bc(b1##S), fb2 = bc(b2##S), fb3 = bc(b3##S);     \
    acc[0][0] = __builtin_amdgcn_mfma_f32_16x16x32_bf16(fa0, fb0, acc[0][0], 0, 0, 0); \
    acc[0][1] = __builtin_amdgcn_mfma_f32_16x16x32_bf16(fa0, fb1, acc[0][1], 0, 0, 0); \
    acc[0][2] = __builtin_amdgcn_mfma_f32_16x16x32_bf16(fa0, fb2, acc[0][2], 0, 0, 0); \
    acc[0][3] = __builtin_amdgcn_mfma_f32_16x16x32_bf16(fa0, fb3, acc[0][3], 0, 0, 0); \
    acc[1][0] = __builtin_amdgcn_mfma_f32_16x16x32_bf16(fa1, fb0, acc[1][0], 0, 0, 0); \
    acc[1][1] = __builtin_amdgcn_mfma_f32_16x16x32_bf16(fa1, fb1, acc[1][1], 0, 0, 0); \
    acc[1][2] = __builtin_amdgcn_mfma_f32_16x16x32_bf16(fa1, fb2, acc[1][2], 0, 0, 0); \
    acc[1][3] = __builtin_amdgcn_mfma_f32_16x16x32_bf16(fa1, fb3, acc[1][3], 0, 0, 0); \
  }

  const int nH = K >> 5;  // halves of 32; K in {256,1024,2048} -> nH in {8,32,64}
  ISSUE(0, 0) ISSUE(1, 1) ISSUE(2, 2) ISSUE(3, 3)
  ISSUE(4, 4) ISSUE(5, 5) ISSUE(6, 6) ISSUE(7, 7)
  int i = 0;
  for (; i + 8 < nH; i += 8) {
    COMPUTE(0) ISSUE(0, i + 8)
    COMPUTE(1) ISSUE(1, i + 9)
    COMPUTE(2) ISSUE(2, i + 10)
    COMPUTE(3) ISSUE(3, i + 11)
    COMPUTE(4) ISSUE(4, i + 12)
    COMPUTE(5) ISSUE(5, i + 13)
    COMPUTE(6) ISSUE(6, i + 14)
    COMPUTE(7) ISSUE(7, i + 15)
  }
  COMPUTE(0) COMPUTE(1) COMPUTE(2) COMPUTE(3)
  COMPUTE(4) COMPUTE(5) COMPUTE(6) COMPUTE(7)
#undef ISSUE
#undef COMPUTE
#undef DECL_SLOT

  // C/D layout: col = lane&15, row = (lane>>4)*4 + reg  [m89-verified]
  const int rb = mw + (kg << 2);
  if (MODE <= MODE_L) {
    float add0 = 0.f, add1 = 0.f, add2 = 0.f, add3 = 0.f;
    if (MODE == MODE_L) {
      add0 = biasP[bn * 64 + jj];
      add1 = biasP[bn * 64 + 16 + jj];
      add2 = biasP[bn * 64 + 32 + jj];
      add3 = biasP[bn * 64 + 48 + jj];
    }
    const int j = bn * 16 + jj;  // hidden unit
#pragma unroll
    for (int m = 0; m < 2; ++m) {
#pragma unroll
      for (int r = 0; r < 4; ++r) {
        int b = rb + m * 16 + r;
        float g0v, g1v, g2v, g3v;
        if (MODE == MODE_L0) {
          const u16* G = Gfull + (size_t)b * 4096 + bn * 64 + jj;
          g0v = acc[m][0][r] + bf2f(G[0]);
          g1v = acc[m][1][r] + bf2f(G[16]);
          g2v = acc[m][2][r] + bf2f(G[32]);
          g3v = acc[m][3][r] + bf2f(G[48]);
        } else {
          g0v = acc[m][0][r] + add0;
          g1v = acc[m][1][r] + add1;
          g2v = acc[m][2][r] + add2;
          g3v = acc[m][3][r] + add3;
        }
        float iv = sigm(g0v), fv = sigm(g1v), gv = tanhfast(g2v), ov = sigm(g3v);
        size_t ci = (size_t)b * 1024 + j;
        float cn = fv * Cst[ci] + iv * gv;
        Cst[ci] = cn;
        Hout[ci] = f2bf(ov * tanhfast(cn));
      }
    }
  } else if (MODE == MODE_FC) {
#pragma unroll
    for (int g = 0; g < 4; ++g) {
      int n = bn * 64 + g * 16 + jj;
      if (n < 204) {
        float bv2 = biasP[n];
#pragma unroll
        for (int m = 0; m < 2; ++m)
#pragma unroll
          for (int r = 0; r < 4; ++r) {
            int b = rb + m * 16 + r;
            outp[((size_t)b * 128 + t) * 204 + n] = acc[m][g][r] + bv2;
          }
      }
    }
  } else if (MODE == MODE_G0) {
#pragma unroll
    for (int g = 0; g < 4; ++g) {
      int P = bn * 64 + g * 16 + jj;
      float bv2 = biasP[P];
#pragma unroll
      for (int m = 0; m < 2; ++m)
#pragma unroll
        for (int r = 0; r < 4; ++r) {
          int b = rb + m * 16 + r;
          Hout[(size_t)b * 4096 + P] = f2bf(acc[m][g][r] + bv2);
        }
    }
  } else {  // MODE_H / MODE_C : init states, cols are orig n = lay*1024 + j
#pragma unroll
    for (int g = 0; g < 4; ++g) {
      int n = bn * 64 + g * 16 + jj;
      int lay = n >> 10, j2 = n & 1023;
      float bv2 = biasP[n];
#pragma unroll
      for (int m = 0; m < 2; ++m)
#pragma unroll
        for (int r = 0; r < 4; ++r) {
          int b = rb + m * 16 + r;
          float v = acc[m][g][r] + bv2;
          if (MODE == MODE_H)
            Hout[(size_t)((lay * 2 + 1) * 256 + b) * 1024 + j2] = f2bf(v);
          else
            outp[(size_t)(lay * 256 + b) * 1024 + j2] = v;
        }
    }
  }
}

// Pipelined step: launch i runs {L0(i), L1(i-1), L2(i-2), fc(i-3)}.
// 392 blocks = 3 jobs x 128 (64 bn-stripes x 2 M-halves) + 8 fc.
// XCD-affine: bid&7 == bn>>3, so the blocks sharing a B-stripe and its
// neighbors land on the same XCD's L2.
__global__ __launch_bounds__(256, 2) void step_kernel(Params p, int i) {
  int bid = blockIdx.x;
  int job, mb, bn;
  if (bid < 384) {
    job = bid >> 7;
    int r = bid & 127;
    bn = (r & 7) * 8 + (r >> 4);  // bn>>3 == bid&7
    mb = (r >> 3) & 1;
  } else {
    job = 3;
    int r = bid - 384;
    mb = r >> 2;
    bn = r & 3;
  }
  int t = i - job;
  if ((unsigned)t >= 128u) return;
  int par = t & 1, pv = par ^ 1;
  u16* HB = p.HB;
#define HBP(lay, pp) (HB + (size_t)(((lay)*2 + (pp)) * 256) * 1024)
  if (job == 0) {
    mm_body<MODE_L0>(HBP(0, pv), nullptr, 1024, 1 << 30, 1024, p.WT0, mb * 128,
                     bn, t, p.G0P, nullptr, p.CC, HBP(0, par), nullptr);
  } else if (job == 1) {
    mm_body<MODE_L>(HBP(0, par), HBP(1, pv), 1024, 1024, 2048, p.WT1, mb * 128,
                    bn, t, nullptr, p.B1P, p.CC + (size_t)256 * 1024,
                    HBP(1, par), nullptr);
  } else if (job == 2) {
    mm_body<MODE_L>(HBP(1, par), HBP(2, pv), 1024, 1024, 2048, p.WT2, mb * 128,
                    bn, t, nullptr, p.B2P, p.CC + (size_t)512 * 1024,
                    HBP(2, par), nullptr);
  } else {
    mm_body<MODE_FC>(HBP(2, par), nullptr, 1024, 1 << 30, 1024, p.FCW, mb * 128,
                     bn, t, nullptr, p.fc_b, nullptr, nullptr, p.out);
  }
#undef HBP
}

// one-time: G0 = x_in@W_ih0+biases (permuted), h/c init = frame@in{h,c}_W + b
__global__ __launch_bounds__(256, 2) void setup_mm(Params p) {
  int bid = blockIdx.x;
  if (bid < 128) {
    mm_body<MODE_G0>(p.FRB, nullptr, 256, 1 << 30, 256, p.WT00,
                     (bid & 1) * 128, bid >> 1, 0, nullptr, p.G0B, nullptr,
                     p.G0P, nullptr);
  } else if (bid < 224) {
    int r = bid - 128;
    mm_body<MODE_H>(p.FRB, nullptr, 256, 1 << 30, 256, p.WIH, (r & 1) * 128,
                    r >> 1, 0, nullptr, p.inh_b, nullptr, p.HB, nullptr);
  } else {
    int r = bid - 224;
    mm_body<MODE_C>(p.FRB, nullptr, 256, 1 << 30, 256, p.WIC, (r & 1) * 128,
                    r >> 1, 0, nullptr, p.inc_b, nullptr, nullptr, p.CC);
  }
}

// fp32 [K][N] sources -> bf16 transposed dst [Nout][Ktot] (K contiguous),
// optional gate permutation of output cols, zero pad k>=Kvalid / n>=Nvalid.
__global__ __launch_bounds__(256) void transpose_bf16(
    const float* __restrict__ srcA, const float* __restrict__ srcB,
    int srcStride, int kSplit, int Kvalid, int Nvalid, int perm,
    u16* __restrict__ dst, int Ktot) {
  __shared__ float tile[64][17];
  int P0 = blockIdx.x * 16;
  int k0 = blockIdx.y * 64;
  int t = threadIdx.x;
  int nl = t & 15;
  int kh = t >> 4;
  int P = P0 + nl;
  int n = perm ? permcol(P) : P;
  bool nok = (n < Nvalid);
#pragma unroll
  for (int q = 0; q < 4; ++q) {
    int kl = q * 16 + kh;
    int k = k0 + kl;
    float v = 0.f;
    if (nok && k < Kvalid) {
      const float* s = (k < kSplit) ? (srcA + (size_t)k * srcStride)
                                    : (srcB + (size_t)(k - kSplit) * srcStride);
      v = s[n];
    }
    tile[kl][nl] = v;
  }
  __syncthreads();
  int jo = t >> 4;
  int kb = (t & 15) << 2;
  unsigned long long pk =
      (unsigned long long)f2bf(tile[kb + 0][jo]) |
      ((unsigned long long)f2bf(tile[kb + 1][jo]) << 16) |
      ((unsigned long long)f2bf(tile[kb + 2][jo]) << 32) |
      ((unsigned long long)f2bf(tile[kb + 3][jo]) << 48);
  *(unsigned long long*)(dst + (size_t)(P0 + jo) * Ktot + k0 + kb) = pk;
}

__global__ __launch_bounds__(256) void build_frame(const float* __restrict__ inputs,
                                                   u16* __restrict__ FRB) {
  int id = blockIdx.x * 256 + threadIdx.x;  // 256*256
  int b = id >> 8, k = id & 255;
  FRB[id] = (k < 204) ? f2bf(inputs[b * 204 + k]) : (u16)0;
}

// G0 bias incl. one-hot label row; layer1/2 combined biases (permuted cols)
__global__ __launch_bounds__(256) void build_bias(
    const float* __restrict__ W_ih0, const float* __restrict__ b_ih0,
    const float* __restrict__ b_hh0, const float* __restrict__ b_ih1,
    const float* __restrict__ b_hh1, const float* __restrict__ b_ih2,
    const float* __restrict__ b_hh2, const int* __restrict__ labels,
    float* __restrict__ G0B, float* __restrict__ B1P, float* __restrict__ B2P) {
  int P = blockIdx.x * 256 + threadIdx.x;  // 4096
  int n = permcol(P);
  int lab = labels[0];
  G0B[P] = W_ih0[(size_t)(204 + lab) * 4096 + n] + b_ih0[n] + b_hh0[n];
  B1P[P] = b_ih1[n] + b_hh1[n];
  B2P[P] = b_ih2[n] + b_hh2[n];
}

extern "C" void kernel_launch(void* const* d_in, const int* in_sizes, int n_in,
                              void* d_out, int out_size, void* d_ws,
                              size_t ws_size, hipStream_t stream) {
  const float* inputs = (const float*)d_in[0];
  const float* W_ih0 = (const float*)d_in[1];
  const float* W_hh0 = (const float*)d_in[2];
  const float* b_ih0 = (const float*)d_in[3];
  const float* b_hh0 = (const float*)d_in[4];
  const float* W_ih1 = (const float*)d_in[5];
  const float* W_hh1 = (const float*)d_in[6];
  const float* b_ih1 = (const float*)d_in[7];
  const float* b_hh1 = (const float*)d_in[8];
  const float* W_ih2 = (const float*)d_in[9];
  const float* W_hh2 = (const float*)d_in[10];
  const float* b_ih2 = (const float*)d_in[11];
  const float* b_hh2 = (const float*)d_in[12];
  const float* fc_W = (const float*)d_in[13];
  const float* fc_b = (const float*)d_in[14];
  const float* inh_W = (const float*)d_in[15];
  const float* inh_b = (const float*)d_in[16];
  const float* inc_W = (const float*)d_in[17];
  const float* inc_b = (const float*)d_in[18];
  const int* labels = (const int*)d_in[19];

  char* ws = (char*)d_ws;
  size_t off = 0;
  auto alloc = [&](size_t bytes) {
    void* r = ws + off;
    off = (off + bytes + 255) & ~(size_t)255;
    return r;
  };
  u16* WT0 = (u16*)alloc(4096ull * 1024 * 2);
  u16* WT1 = (u16*)alloc(4096ull * 2048 * 2);
  u16* WT2 = (u16*)alloc(4096ull * 2048 * 2);
  u16* WT00 = (u16*)alloc(4096ull * 256 * 2);
  u16* FCW = (u16*)alloc(256ull * 1024 * 2);
  u16* WIH = (u16*)alloc(3072ull * 256 * 2);
  u16* WIC = (u16*)alloc(3072ull * 256 * 2);
  u16* FRB = (u16*)alloc(256ull * 256 * 2);
  u16* HB = (u16*)alloc(3ull * 2 * 256 * 1024 * 2);
  u16* G0P = (u16*)alloc(256ull * 4096 * 2);
  float* G0B = (float*)alloc(4096ull * 4);
  float* B1P = (float*)alloc(4096ull * 4);
  float* B2P = (float*)alloc(4096ull * 4);
  float* CC = (float*)alloc(3ull * 256 * 1024 * 4);
  if (off > ws_size) return;  // workspace too small: fail loudly (validation)

  const int BIG = 1 << 30;
  // weight repack (one-time per call)
  transpose_bf16<<<dim3(256, 16), 256, 0, stream>>>(W_hh0, nullptr, 4096, BIG, 1024, 4096, 1, WT0, 1024);
  transpose_bf16<<<dim3(256, 32), 256, 0, stream>>>(W_ih1, W_hh1, 4096, 1024, 2048, 4096, 1, WT1, 2048);
  transpose_bf16<<<dim3(256, 32), 256, 0, stream>>>(W_ih2, W_hh2, 4096, 1024, 2048, 4096, 1, WT2, 2048);
  transpose_bf16<<<dim3(256, 4), 256, 0, stream>>>(W_ih0, nullptr, 4096, BIG, 204, 4096, 1, WT00, 256);
  transpose_bf16<<<dim3(16, 16), 256, 0, stream>>>(fc_W, nullptr, 204, BIG, 1024, 204, 0, FCW, 1024);
  transpose_bf16<<<dim3(192, 4), 256, 0, stream>>>(inh_W, nullptr, 3072, BIG, 204, 3072, 0, WIH, 256);
  transpose_bf16<<<dim3(192, 4), 256, 0, stream>>>(inc_W, nullptr, 3072, BIG, 204, 3072, 0, WIC, 256);
  build_frame<<<256, 256, 0, stream>>>(inputs, FRB);
  build_bias<<<16, 256, 0, stream>>>(W_ih0, b_ih0, b_hh0, b_ih1, b_hh1, b_ih2,
                                     b_hh2, labels, G0B, B1P, B2P);

  Params p;
  p.fc_b = fc_b; p.inh_b = inh_b; p.inc_b = inc_b;
  p.WT0 = WT0; p.WT1 = WT1; p.WT2 = WT2; p.WT00 = WT00; p.FCW = FCW;
  p.WIH = WIH; p.WIC = WIC; p.FRB = FRB; p.HB = HB;
  p.G0P = G0P; p.G0B = G0B; p.B1P = B1P; p.B2P = B2P; p.CC = CC;
  p.out = (float*)d_out;

  setup_mm<<<320, 256, 0, stream>>>(p);

  // pipelined steps: i = 0..130
  for (int i = 0; i <= 130; ++i)
    step_kernel<<<392, 256, 0, stream>>>(p, i);
}

// Round 7
// 12976.950 us; speedup vs baseline: 1.7524x; 1.7524x over previous
//
#include <hip/hip_runtime.h>

// DecoderRNN: 3-layer LSTM (H=1024) + fc, B=256, 128 steps, constant input.
// bf16 MFMA 16x16x32; gate-interleaved weight columns so the LSTM cell update
// is lane-local in the matmul epilogue.
// Persistent PLAIN-LAUNCH kernel (no cooperative API — it failed to launch in
// R6): 392 blocks, capacity-guaranteed co-resident via __launch_bounds__(256,2)
// (VGPR<=128 -> >=2 blocks/CU; LDS 24KB -> 6/CU; 392 <= 512). Runs the whole
// pipelined sequence {L0(i),L1(i-1),L2(i-2),fc(i-3)} with a two-level software
// grid barrier + agent-scope fences between steps.

#define DEVINL static __device__ __forceinline__

typedef __bf16 bf16x8 __attribute__((ext_vector_type(8)));
typedef float f32x4 __attribute__((ext_vector_type(4)));
typedef unsigned short u16;
typedef unsigned int u32;

DEVINL u16 f2bf(float f) {
  u32 u = __builtin_bit_cast(u32, f);
  u += 0x7fffu + ((u >> 16) & 1u);  // RNE
  return (u16)(u >> 16);
}
DEVINL float bf2f(u16 h) {
  u32 u = (u32)h << 16;
  return __builtin_bit_cast(float, u);
}
DEVINL float sigm(float x) { return 1.0f / (1.0f + __expf(-x)); }
DEVINL float tanhfast(float x) { return 1.0f - 2.0f / (1.0f + __expf(2.0f * x)); }

// permuted column index -> original gate column: P = grp*64 + g*16 + jj
// maps hidden unit j = grp*16+jj, gate g  ->  orig n = g*1024 + j
DEVINL int permcol(int P) {
  int grp = P >> 6, g = (P >> 4) & 3, jj = P & 15;
  return g * 1024 + grp * 16 + jj;
}

struct Params {
  const float* fc_b;
  const float* inh_b;
  const float* inc_b;
  const u16 *WT0, *WT1, *WT2, *WT00, *FCW, *WIH, *WIC, *FRB;
  u16* HB;   // h state bf16: [layer][parity][256][1024]
  u16* G0P;  // precomputed layer0 input gates, bf16 [256][4096]
  float *G0B, *B1P, *B2P, *CC;  // CC: c state fp32 [layer][256][1024]
  float* out;
};

#define MODE_L0 0
#define MODE_L 1
#define MODE_FC 2
#define MODE_G0 3
#define MODE_H 4
#define MODE_C 5

DEVINL void issue_tile(uint4 (&av)[4], uint4 (&bv)[2], int kt, const u16* A0,
                       const u16* A1, int kSplit, int sA, int K, const u16* Wt,
                       int m0, int wrow, const int (&rq)[4], const int (&kq)[4]) {
  const u16* Ab = (kt < kSplit) ? (A0 + kt) : (A1 + (kt - kSplit));
#pragma unroll
  for (int q = 0; q < 4; ++q)
    av[q] = *(const uint4*)(Ab + (size_t)(m0 + rq[q]) * sA + kq[q] * 8);
  const u16* Bb = Wt + kt;
#pragma unroll
  for (int q = 0; q < 2; ++q)
    bv[q] = *(const uint4*)(Bb + (size_t)(wrow + rq[q]) * K + kq[q] * 8);
}

DEVINL void write_tile(u16* Al, u16* Bl, const uint4 (&av)[4],
                       const uint4 (&bv)[2], const int (&rq)[4],
                       const int (&kq)[4]) {
#pragma unroll
  for (int q = 0; q < 4; ++q)
    *(uint4*)(Al + (rq[q] * 8 + (kq[q] ^ (rq[q] & 7))) * 8) = av[q];
#pragma unroll
  for (int q = 0; q < 2; ++q)
    *(uint4*)(Bl + (rq[q] * 8 + (kq[q] ^ (rq[q] & 7))) * 8) = bv[q];
}

DEVINL void mfma_tile(const u16* Al, const u16* Bl, f32x4 (&acc)[2][4], int rl0,
                      int hh, int e7, int jj) {
#pragma unroll
  for (int kk = 0; kk < 2; ++kk) {
    int sl = (((kk << 2) | hh) ^ e7) * 8;
    bf16x8 a0 = *(const bf16x8*)(Al + rl0 * 64 + sl);
    bf16x8 a1 = *(const bf16x8*)(Al + (rl0 + 16) * 64 + sl);
    bf16x8 b0 = *(const bf16x8*)(Bl + (jj)*64 + sl);
    bf16x8 b1 = *(const bf16x8*)(Bl + (16 + jj) * 64 + sl);
    bf16x8 b2 = *(const bf16x8*)(Bl + (32 + jj) * 64 + sl);
    bf16x8 b3 = *(const bf16x8*)(Bl + (48 + jj) * 64 + sl);
    acc[0][0] = __builtin_amdgcn_mfma_f32_16x16x32_bf16(a0, b0, acc[0][0], 0, 0, 0);
    acc[0][1] = __builtin_amdgcn_mfma_f32_16x16x32_bf16(a0, b1, acc[0][1], 0, 0, 0);
    acc[0][2] = __builtin_amdgcn_mfma_f32_16x16x32_bf16(a0, b2, acc[0][2], 0, 0, 0);
    acc[0][3] = __builtin_amdgcn_mfma_f32_16x16x32_bf16(a0, b3, acc[0][3], 0, 0, 0);
    acc[1][0] = __builtin_amdgcn_mfma_f32_16x16x32_bf16(a1, b0, acc[1][0], 0, 0, 0);
    acc[1][1] = __builtin_amdgcn_mfma_f32_16x16x32_bf16(a1, b1, acc[1][1], 0, 0, 0);
    acc[1][2] = __builtin_amdgcn_mfma_f32_16x16x32_bf16(a1, b2, acc[1][2], 0, 0, 0);
    acc[1][3] = __builtin_amdgcn_mfma_f32_16x16x32_bf16(a1, b3, acc[1][3], 0, 0, 0);
  }
}

// Block: 256 threads = 4 waves, output tile 128(M) x 64(N). Waves stacked in
// M, each wave 32 rows x 64 cols = 2 M-frags x 4 N-frags of 16x16x32 MFMA.
// LDS tiles [rows][64 k] bf16, 128B rows; slot-XOR swizzle: LDS[row][slot ^
// (row&7)] holds global slot `slot` (slot = 8-elem granule of k).
template <int MODE>
DEVINL void mm_body(u16* Al, u16* Bl, const u16* A0, const u16* A1, int sA,
                    int kSplit, int K, const u16* Wt, int m0, int bn, int t,
                    const u16* Gfull, const float* biasP, float* Cst, u16* Hout,
                    float* outp) {
  const int tid = threadIdx.x;
  const int l = tid & 63;
  const int w = tid >> 6;
  const int hh = (l >> 4) & 3;
  const int jj = l & 15;
  const int rl0 = w * 32 + jj;  // A row of m=0 frag (row&7 == l&7)
  const int e7 = l & 7;

  int rq[4], kq[4];
#pragma unroll
  for (int q = 0; q < 4; ++q) {
    int L = tid + q * 256;
    rq[q] = L >> 3;
    kq[q] = L & 7;
  }

  f32x4 acc[2][4];
#pragma unroll
  for (int m = 0; m < 2; ++m)
#pragma unroll
    for (int g = 0; g < 4; ++g) acc[m][g] = (f32x4){0.f, 0.f, 0.f, 0.f};

  const int wrow = bn * 64;  // B tile row base in WT
  uint4 av0[4], bv0[2], av1[4], bv1[2];

  // depth-2 prologue: tiles 0 and 64 in flight (K >= 256 always)
  issue_tile(av0, bv0, 0, A0, A1, kSplit, sA, K, Wt, m0, wrow, rq, kq);
  issue_tile(av1, bv1, 64, A0, A1, kSplit, sA, K, Wt, m0, wrow, rq, kq);

  for (int k0 = 0; k0 < K; k0 += 128) {
    __builtin_amdgcn_s_barrier();          // prev tile's LDS readers done
    write_tile(Al, Bl, av0, bv0, rq, kq);  // counted vmcnt gates these writes
    if (k0 + 128 < K)
      issue_tile(av0, bv0, k0 + 128, A0, A1, kSplit, sA, K, Wt, m0, wrow, rq, kq);
    asm volatile("s_waitcnt lgkmcnt(0)" ::: "memory");
    __builtin_amdgcn_s_barrier();
    mfma_tile(Al, Bl, acc, rl0, hh, e7, jj);

    __builtin_amdgcn_s_barrier();
    write_tile(Al, Bl, av1, bv1, rq, kq);
    if (k0 + 192 < K)
      issue_tile(av1, bv1, k0 + 192, A0, A1, kSplit, sA, K, Wt, m0, wrow, rq, kq);
    asm volatile("s_waitcnt lgkmcnt(0)" ::: "memory");
    __builtin_amdgcn_s_barrier();
    mfma_tile(Al, Bl, acc, rl0, hh, e7, jj);
  }

  // C/D layout: col = lane&15, row = (lane>>4)*4 + reg  [m89-verified]
  const int rb = m0 + w * 32 + (hh << 2);
  if (MODE <= MODE_L) {
    float add0 = 0.f, add1 = 0.f, add2 = 0.f, add3 = 0.f;
    if (MODE == MODE_L) {
      add0 = biasP[bn * 64 + jj];
      add1 = biasP[bn * 64 + 16 + jj];
      add2 = biasP[bn * 64 + 32 + jj];
      add3 = biasP[bn * 64 + 48 + jj];
    }
    const int j = bn * 16 + jj;  // hidden unit
#pragma unroll
    for (int m = 0; m < 2; ++m) {
#pragma unroll
      for (int r = 0; r < 4; ++r) {
        int b = rb + m * 16 + r;
        float g0v, g1v, g2v, g3v;
        if (MODE == MODE_L0) {
          const u16* G = Gfull + (size_t)b * 4096 + bn * 64 + jj;
          g0v = acc[m][0][r] + bf2f(G[0]);
          g1v = acc[m][1][r] + bf2f(G[16]);
          g2v = acc[m][2][r] + bf2f(G[32]);
          g3v = acc[m][3][r] + bf2f(G[48]);
        } else {
          g0v = acc[m][0][r] + add0;
          g1v = acc[m][1][r] + add1;
          g2v = acc[m][2][r] + add2;
          g3v = acc[m][3][r] + add3;
        }
        float iv = sigm(g0v), fv = sigm(g1v), gv = tanhfast(g2v), ov = sigm(g3v);
        size_t ci = (size_t)b * 1024 + j;
        float cn = fv * Cst[ci] + iv * gv;
        Cst[ci] = cn;
        Hout[ci] = f2bf(ov * tanhfast(cn));
      }
    }
  } else if (MODE == MODE_FC) {
#pragma unroll
    for (int g = 0; g < 4; ++g) {
      int n = bn * 64 + g * 16 + jj;
      if (n < 204) {
        float bv2 = biasP[n];
#pragma unroll
        for (int m = 0; m < 2; ++m)
#pragma unroll
          for (int r = 0; r < 4; ++r) {
            int b = rb + m * 16 + r;
            outp[((size_t)b * 128 + t) * 204 + n] = acc[m][g][r] + bv2;
          }
      }
    }
  } else if (MODE == MODE_G0) {
#pragma unroll
    for (int g = 0; g < 4; ++g) {
      int P = bn * 64 + g * 16 + jj;
      float bv2 = biasP[P];
#pragma unroll
      for (int m = 0; m < 2; ++m)
#pragma unroll
        for (int r = 0; r < 4; ++r) {
          int b = rb + m * 16 + r;
          Hout[(size_t)b * 4096 + P] = f2bf(acc[m][g][r] + bv2);
        }
    }
  } else {  // MODE_H / MODE_C : init states, cols are orig n = lay*1024 + j
#pragma unroll
    for (int g = 0; g < 4; ++g) {
      int n = bn * 64 + g * 16 + jj;
      int lay = n >> 10, j2 = n & 1023;
      float bv2 = biasP[n];
#pragma unroll
      for (int m = 0; m < 2; ++m)
#pragma unroll
        for (int r = 0; r < 4; ++r) {
          int b = rb + m * 16 + r;
          float v = acc[m][g][r] + bv2;
          if (MODE == MODE_H)
            Hout[(size_t)((lay * 2 + 1) * 256 + b) * 1024 + j2] = f2bf(v);
          else
            outp[(size_t)(lay * 256 + b) * 1024 + j2] = v;
        }
    }
  }
}

// Two-level software grid barrier. All 392 blocks are co-resident by capacity
// (see launch_bounds note at persist_kernel). Relaxed agent-scope polls with
// s_sleep; one release/acquire agent fence pair per block per step gives
// cross-XCD visibility of h-state (G16).
DEVINL void grid_barrier(u32* bar, int bid, int ep) {
  __syncthreads();  // drains this block's stores (vmcnt0 before s_barrier)
  if (threadIdx.x == 0) {
    __builtin_amdgcn_fence(__ATOMIC_RELEASE, "agent");  // wb dirty L2
    __hip_atomic_fetch_add(bar + (bid & 7) * 64, 1u, __ATOMIC_RELAXED,
                           __HIP_MEMORY_SCOPE_AGENT);
    if (bid == 0) {
#pragma unroll 1
      for (int g = 0; g < 8; ++g)
        while (__hip_atomic_load(bar + g * 64, __ATOMIC_RELAXED,
                                 __HIP_MEMORY_SCOPE_AGENT) < (u32)ep * 49u)
          __builtin_amdgcn_s_sleep(8);
      __hip_atomic_store(bar + 512, (u32)ep, __ATOMIC_RELAXED,
                         __HIP_MEMORY_SCOPE_AGENT);
    } else {
#pragma unroll 1
      while (__hip_atomic_load(bar + 512, __ATOMIC_RELAXED,
                               __HIP_MEMORY_SCOPE_AGENT) < (u32)ep)
        __builtin_amdgcn_s_sleep(8);
    }
    __builtin_amdgcn_fence(__ATOMIC_ACQUIRE, "agent");  // inv stale caches
  }
  __syncthreads();
}

// Persistent pipelined kernel, PLAIN launch. 392 blocks: jobs 0..2 have 128
// blocks each (64 bn-stripes x 2 M-halves), fc 8. bid&7 ~ XCD affinity
// (bn>>3 == bid&7) and barrier group (49 blocks each).
// Capacity: LDS 24KB -> 6 blocks/CU; launch_bounds(256,2) -> VGPR<=128 ->
// >=2 blocks/CU; grid 392 <= 2*256 -> all blocks resident, barrier is safe.
__global__ __launch_bounds__(256, 2) void persist_kernel(Params p, u32* bar) {
  __shared__ u16 Al[128 * 64];
  __shared__ u16 Bl[64 * 64];
  const int bid = blockIdx.x;
  int job, mb, bn;
  if (bid < 384) {
    job = bid >> 7;
    int r = bid & 127;
    bn = (r & 7) * 8 + (r >> 4);  // bn>>3 == bid&7 (XCD-affine weight slice)
    mb = (r >> 3) & 1;
  } else {
    job = 3;
    int r = bid - 384;
    mb = r >> 2;
    bn = r & 3;
  }
  u16* HB = p.HB;
#define HBP(lay, pp) (HB + (size_t)(((lay)*2 + (pp)) * 256) * 1024)
  for (int i = 0; i <= 130; ++i) {
    int t = i - job;
    if ((unsigned)t < 128u) {
      int par = t & 1, pv = par ^ 1;
      if (job == 0) {
        mm_body<MODE_L0>(Al, Bl, HBP(0, pv), nullptr, 1024, 1 << 30, 1024,
                         p.WT0, mb * 128, bn, t, p.G0P, nullptr, p.CC,
                         HBP(0, par), nullptr);
      } else if (job == 1) {
        mm_body<MODE_L>(Al, Bl, HBP(0, par), HBP(1, pv), 1024, 1024, 2048,
                        p.WT1, mb * 128, bn, t, nullptr, p.B1P,
                        p.CC + (size_t)256 * 1024, HBP(1, par), nullptr);
      } else if (job == 2) {
        mm_body<MODE_L>(Al, Bl, HBP(1, par), HBP(2, pv), 1024, 1024, 2048,
                        p.WT2, mb * 128, bn, t, nullptr, p.B2P,
                        p.CC + (size_t)512 * 1024, HBP(2, par), nullptr);
      } else {
        mm_body<MODE_FC>(Al, Bl, HBP(2, par), nullptr, 1024, 1 << 30, 1024,
                         p.FCW, mb * 128, bn, t, nullptr, p.fc_b, nullptr,
                         nullptr, p.out);
      }
    }
    if (i < 130) grid_barrier(bar, bid, i + 1);
  }
#undef HBP
}

// one-time: G0 = x_in@W_ih0+biases (permuted), h/c init = frame@in{h,c}_W + b
__global__ __launch_bounds__(256) void setup_mm(Params p) {
  __shared__ u16 Al[128 * 64];
  __shared__ u16 Bl[64 * 64];
  int bid = blockIdx.x;
  if (bid < 128) {
    mm_body<MODE_G0>(Al, Bl, p.FRB, nullptr, 256, 1 << 30, 256, p.WT00,
                     (bid >> 6) * 128, bid & 63, 0, nullptr, p.G0B, nullptr,
                     p.G0P, nullptr);
  } else if (bid < 224) {
    int b2 = bid - 128;
    mm_body<MODE_H>(Al, Bl, p.FRB, nullptr, 256, 1 << 30, 256, p.WIH,
                    (b2 / 48) * 128, b2 % 48, 0, nullptr, p.inh_b, nullptr,
                    p.HB, nullptr);
  } else {
    int b2 = bid - 224;
    mm_body<MODE_C>(Al, Bl, p.FRB, nullptr, 256, 1 << 30, 256, p.WIC,
                    (b2 / 48) * 128, b2 % 48, 0, nullptr, p.inc_b, nullptr,
                    nullptr, p.CC);
  }
}

// fp32 [K][N] sources -> bf16 transposed dst [Nout][Ktot] (K contiguous),
// optional gate permutation of output cols, zero pad k>=Kvalid / n>=Nvalid.
__global__ __launch_bounds__(256) void transpose_bf16(
    const float* __restrict__ srcA, const float* __restrict__ srcB,
    int srcStride, int kSplit, int Kvalid, int Nvalid, int perm,
    u16* __restrict__ dst, int Ktot) {
  __shared__ float tile[64][17];
  int P0 = blockIdx.x * 16;
  int k0 = blockIdx.y * 64;
  int t = threadIdx.x;
  int nl = t & 15;
  int kh = t >> 4;
  int P = P0 + nl;
  int n = perm ? permcol(P) : P;
  bool nok = (n < Nvalid);
#pragma unroll
  for (int q = 0; q < 4; ++q) {
    int kl = q * 16 + kh;
    int k = k0 + kl;
    float v = 0.f;
    if (nok && k < Kvalid) {
      const float* s = (k < kSplit) ? (srcA + (size_t)k * srcStride)
                                    : (srcB + (size_t)(k - kSplit) * srcStride);
      v = s[n];
    }
    tile[kl][nl] = v;
  }
  __syncthreads();
  int jo = t >> 4;
  int kb = (t & 15) << 2;
  unsigned long long pk =
      (unsigned long long)f2bf(tile[kb + 0][jo]) |
      ((unsigned long long)f2bf(tile[kb + 1][jo]) << 16) |
      ((unsigned long long)f2bf(tile[kb + 2][jo]) << 32) |
      ((unsigned long long)f2bf(tile[kb + 3][jo]) << 48);
  *(unsigned long long*)(dst + (size_t)(P0 + jo) * Ktot + k0 + kb) = pk;
}

__global__ __launch_bounds__(256) void build_frame(const float* __restrict__ inputs,
                                                   u16* __restrict__ FRB) {
  int id = blockIdx.x * 256 + threadIdx.x;  // 256*256
  int b = id >> 8, k = id & 255;
  FRB[id] = (k < 204) ? f2bf(inputs[b * 204 + k]) : (u16)0;
}

// G0 bias incl. one-hot label row; layer1/2 combined biases (permuted cols)
__global__ __launch_bounds__(256) void build_bias(
    const float* __restrict__ W_ih0, const float* __restrict__ b_ih0,
    const float* __restrict__ b_hh0, const float* __restrict__ b_ih1,
    const float* __restrict__ b_hh1, const float* __restrict__ b_ih2,
    const float* __restrict__ b_hh2, const int* __restrict__ labels,
    float* __restrict__ G0B, float* __restrict__ B1P, float* __restrict__ B2P) {
  int P = blockIdx.x * 256 + threadIdx.x;  // 4096
  int n = permcol(P);
  int lab = labels[0];
  G0B[P] = W_ih0[(size_t)(204 + lab) * 4096 + n] + b_ih0[n] + b_hh0[n];
  B1P[P] = b_ih1[n] + b_hh1[n];
  B2P[P] = b_ih2[n] + b_hh2[n];
}

extern "C" void kernel_launch(void* const* d_in, const int* in_sizes, int n_in,
                              void* d_out, int out_size, void* d_ws,
                              size_t ws_size, hipStream_t stream) {
  const float* inputs = (const float*)d_in[0];
  const float* W_ih0 = (const float*)d_in[1];
  const float* W_hh0 = (const float*)d_in[2];
  const float* b_ih0 = (const float*)d_in[3];
  const float* b_hh0 = (const float*)d_in[4];
  const float* W_ih1 = (const float*)d_in[5];
  const float* W_hh1 = (const float*)d_in[6];
  const float* b_ih1 = (const float*)d_in[7];
  const float* b_hh1 = (const float*)d_in[8];
  const float* W_ih2 = (const float*)d_in[9];
  const float* W_hh2 = (const float*)d_in[10];
  const float* b_ih2 = (const float*)d_in[11];
  const float* b_hh2 = (const float*)d_in[12];
  const float* fc_W = (const float*)d_in[13];
  const float* fc_b = (const float*)d_in[14];
  const float* inh_W = (const float*)d_in[15];
  const float* inh_b = (const float*)d_in[16];
  const float* inc_W = (const float*)d_in[17];
  const float* inc_b = (const float*)d_in[18];
  const int* labels = (const int*)d_in[19];

  char* ws = (char*)d_ws;
  size_t off = 0;
  auto alloc = [&](size_t bytes) {
    void* r = ws + off;
    off = (off + bytes + 255) & ~(size_t)255;
    return r;
  };
  u16* WT0 = (u16*)alloc(4096ull * 1024 * 2);
  u16* WT1 = (u16*)alloc(4096ull * 2048 * 2);
  u16* WT2 = (u16*)alloc(4096ull * 2048 * 2);
  u16* WT00 = (u16*)alloc(4096ull * 256 * 2);
  u16* FCW = (u16*)alloc(256ull * 1024 * 2);
  u16* WIH = (u16*)alloc(3072ull * 256 * 2);
  u16* WIC = (u16*)alloc(3072ull * 256 * 2);
  u16* FRB = (u16*)alloc(256ull * 256 * 2);
  u16* HB = (u16*)alloc(3ull * 2 * 256 * 1024 * 2);
  u16* G0P = (u16*)alloc(256ull * 4096 * 2);
  float* G0B = (float*)alloc(4096ull * 4);
  float* B1P = (float*)alloc(4096ull * 4);
  float* B2P = (float*)alloc(4096ull * 4);
  float* CC = (float*)alloc(3ull * 256 * 1024 * 4);
  u32* BAR = (u32*)alloc(4096);  // 8 group counters (64-u32 apart) + flag @512
  if (off > ws_size) return;  // workspace too small: fail loudly (validation)

  const int BIG = 1 << 30;
  // weight repack (one-time per call)
  transpose_bf16<<<dim3(256, 16), 256, 0, stream>>>(W_hh0, nullptr, 4096, BIG, 1024, 4096, 1, WT0, 1024);
  transpose_bf16<<<dim3(256, 32), 256, 0, stream>>>(W_ih1, W_hh1, 4096, 1024, 2048, 4096, 1, WT1, 2048);
  transpose_bf16<<<dim3(256, 32), 256, 0, stream>>>(W_ih2, W_hh2, 4096, 1024, 2048, 4096, 1, WT2, 2048);
  transpose_bf16<<<dim3(256, 4), 256, 0, stream>>>(W_ih0, nullptr, 4096, BIG, 204, 4096, 1, WT00, 256);
  transpose_bf16<<<dim3(16, 16), 256, 0, stream>>>(fc_W, nullptr, 204, BIG, 1024, 204, 0, FCW, 1024);
  transpose_bf16<<<dim3(192, 4), 256, 0, stream>>>(inh_W, nullptr, 3072, BIG, 204, 3072, 0, WIH, 256);
  transpose_bf16<<<dim3(192, 4), 256, 0, stream>>>(inc_W, nullptr, 3072, BIG, 204, 3072, 0, WIC, 256);
  build_frame<<<256, 256, 0, stream>>>(inputs, FRB);
  build_bias<<<16, 256, 0, stream>>>(W_ih0, b_ih0, b_hh0, b_ih1, b_hh1, b_ih2,
                                     b_hh2, labels, G0B, B1P, B2P);
  hipMemsetAsync(BAR, 0, 4096, stream);

  Params p;
  p.fc_b = fc_b; p.inh_b = inh_b; p.inc_b = inc_b;
  p.WT0 = WT0; p.WT1 = WT1; p.WT2 = WT2; p.WT00 = WT00; p.FCW = FCW;
  p.WIH = WIH; p.WIC = WIC; p.FRB = FRB; p.HB = HB;
  p.G0P = G0P; p.G0B = G0B; p.B1P = B1P; p.B2P = B2P; p.CC = CC;
  p.out = (float*)d_out;

  setup_mm<<<320, 256, 0, stream>>>(p);

  // persistent pipelined sequence: one plain launch, software grid barrier
  persist_kernel<<<392, 256, 0, stream>>>(p, BAR);
}

// Round 8
// 5284.912 us; speedup vs baseline: 4.3030x; 2.4555x over previous
//
#include <hip/hip_runtime.h>

// DecoderRNN: 3-layer LSTM (H=1024) + fc, B=256, 128 steps, constant input.
// bf16 MFMA 16x16x32; gate-interleaved weight columns; persistent plain-launch
// kernel with software grid barrier.
// THIS ROUND: no acquire fence (weights stay warm in L2); h-state read via
// coherent global_load_lds (aux=sc0|sc1 -> served from MALL); release fence
// (writeback-only) pushes h to MALL each step; direct-to-LDS staging with
// counted vmcnt(6) and source-side swizzle.

#define DEVINL static __device__ __forceinline__

typedef __bf16 bf16x8 __attribute__((ext_vector_type(8)));
typedef float f32x4 __attribute__((ext_vector_type(4)));
typedef unsigned short u16;
typedef unsigned int u32;

DEVINL u16 f2bf(float f) {
  u32 u = __builtin_bit_cast(u32, f);
  u += 0x7fffu + ((u >> 16) & 1u);  // RNE
  return (u16)(u >> 16);
}
DEVINL float bf2f(u16 h) {
  u32 u = (u32)h << 16;
  return __builtin_bit_cast(float, u);
}
DEVINL float sigm(float x) { return 1.0f / (1.0f + __expf(-x)); }
DEVINL float tanhfast(float x) { return 1.0f - 2.0f / (1.0f + __expf(2.0f * x)); }

// coherent (device-scope, bypass L2) global->LDS: aux = sc0|sc1 = 1|16
DEVINL void glds_coh(const u16* g, u16* l) {
  __builtin_amdgcn_global_load_lds(
      (const __attribute__((address_space(1))) u32*)g,
      (__attribute__((address_space(3))) u32*)l, 16, 0, 17);
}
// normal cached global->LDS (weights; stay resident in per-XCD L2)
DEVINL void glds(const u16* g, u16* l) {
  __builtin_amdgcn_global_load_lds(
      (const __attribute__((address_space(1))) u32*)g,
      (__attribute__((address_space(3))) u32*)l, 16, 0, 0);
}

// permuted column index -> original gate column: P = grp*64 + g*16 + jj
DEVINL int permcol(int P) {
  int grp = P >> 6, g = (P >> 4) & 3, jj = P & 15;
  return g * 1024 + grp * 16 + jj;
}

struct Params {
  const float* fc_b;
  const float* inh_b;
  const float* inc_b;
  const u16 *WT0, *WT1, *WT2, *WT00, *FCW, *WIH, *WIC, *FRB;
  u16* HB;   // h state bf16: [layer][parity][256][1024]
  u16* G0P;  // precomputed layer0 input gates, bf16 [256][4096]
  float *G0B, *B1P, *B2P, *CC;  // CC: c state fp32 [layer][256][1024]
  float* out;
};

#define MODE_L0 0
#define MODE_L 1
#define MODE_FC 2
#define MODE_G0 3
#define MODE_H 4
#define MODE_C 5

// issue one 64-K tile: 4 A-loads (coherent) + 2 B-loads (cached) per thread,
// direct to LDS. LDS layout linear (HW: wave base + lane*16); the XOR swizzle
// is applied on the GLOBAL source granule (kqs = kq ^ (row&7)), so LDS[row][s]
// holds global granule s^(row&7) — identical content to the reg-staged version.
DEVINL void issue_tile(int kt, const u16* A0, const u16* A1, int kSplit, int sA,
                       int K, const u16* Wt, int m0, int wrow,
                       const int (&rq)[4], const int (&kqs)[4],
                       const int (&lo)[4], u16* Abuf, u16* Bbuf) {
  const u16* Ab = (kt < kSplit) ? (A0 + kt) : (A1 + (kt - kSplit));
#pragma unroll
  for (int q = 0; q < 4; ++q)
    glds_coh(Ab + (size_t)(m0 + rq[q]) * sA + kqs[q] * 8, Abuf + lo[q]);
  const u16* Bb = Wt + kt;
#pragma unroll
  for (int q = 0; q < 2; ++q)
    glds(Bb + (size_t)(wrow + rq[q]) * K + kqs[q] * 8, Bbuf + lo[q]);
}

DEVINL void mfma_tile(const u16* Al, const u16* Bl, f32x4 (&acc)[2][4], int rl0,
                      int hh, int e7, int jj) {
#pragma unroll
  for (int kk = 0; kk < 2; ++kk) {
    int sl = (((kk << 2) | hh) ^ e7) * 8;
    bf16x8 a0 = *(const bf16x8*)(Al + rl0 * 64 + sl);
    bf16x8 a1 = *(const bf16x8*)(Al + (rl0 + 16) * 64 + sl);
    bf16x8 b0 = *(const bf16x8*)(Bl + (jj)*64 + sl);
    bf16x8 b1 = *(const bf16x8*)(Bl + (16 + jj) * 64 + sl);
    bf16x8 b2 = *(const bf16x8*)(Bl + (32 + jj) * 64 + sl);
    bf16x8 b3 = *(const bf16x8*)(Bl + (48 + jj) * 64 + sl);
    acc[0][0] = __builtin_amdgcn_mfma_f32_16x16x32_bf16(a0, b0, acc[0][0], 0, 0, 0);
    acc[0][1] = __builtin_amdgcn_mfma_f32_16x16x32_bf16(a0, b1, acc[0][1], 0, 0, 0);
    acc[0][2] = __builtin_amdgcn_mfma_f32_16x16x32_bf16(a0, b2, acc[0][2], 0, 0, 0);
    acc[0][3] = __builtin_amdgcn_mfma_f32_16x16x32_bf16(a0, b3, acc[0][3], 0, 0, 0);
    acc[1][0] = __builtin_amdgcn_mfma_f32_16x16x32_bf16(a1, b0, acc[1][0], 0, 0, 0);
    acc[1][1] = __builtin_amdgcn_mfma_f32_16x16x32_bf16(a1, b1, acc[1][1], 0, 0, 0);
    acc[1][2] = __builtin_amdgcn_mfma_f32_16x16x32_bf16(a1, b2, acc[1][2], 0, 0, 0);
    acc[1][3] = __builtin_amdgcn_mfma_f32_16x16x32_bf16(a1, b3, acc[1][3], 0, 0, 0);
  }
}

// Block: 256 threads = 4 waves, output tile 128(M) x 64(N); wave w = rows
// [w*32, w*32+32): 2 M-frags x 4 N-frags. LDS double-buffered [2][rows][64k].
// Counted vmcnt(6): exactly one 6-load group completes per iteration; the
// next group stays in flight across both barriers.
template <int MODE>
DEVINL void mm_body(u16* Al, u16* Bl, const u16* A0, const u16* A1, int sA,
                    int kSplit, int K, const u16* Wt, int m0, int bn, int t,
                    const u16* Gfull, const float* biasP, float* Cst, u16* Hout,
                    float* outp) {
  const int tid = threadIdx.x;
  const int l = tid & 63;
  const int w = tid >> 6;
  const int hh = (l >> 4) & 3;
  const int jj = l & 15;
  const int rl0 = w * 32 + jj;
  const int e7 = l & 7;

  int rq[4], kqs[4], lo[4];
#pragma unroll
  for (int q = 0; q < 4; ++q) {
    int L = tid + q * 256;
    rq[q] = L >> 3;
    kqs[q] = (L & 7) ^ (rq[q] & 7);       // source-swizzled granule
    lo[q] = ((tid & ~63) + q * 256) * 8;  // wave-uniform LDS base (u16 units)
  }

  f32x4 acc[2][4];
#pragma unroll
  for (int m = 0; m < 2; ++m)
#pragma unroll
    for (int g = 0; g < 4; ++g) acc[m][g] = (f32x4){0.f, 0.f, 0.f, 0.f};

  const int wrow = bn * 64;
  const int n = K >> 6;  // 64-K tiles; n in {4,16,32}

  issue_tile(0, A0, A1, kSplit, sA, K, Wt, m0, wrow, rq, kqs, lo, Al, Bl);
  issue_tile(64, A0, A1, kSplit, sA, K, Wt, m0, wrow, rq, kqs, lo, Al + 8192,
             Bl + 4096);

  for (int j = 0; j < n; ++j) {
    u16* Ac = Al + (j & 1) * 8192;
    u16* Bc = Bl + (j & 1) * 4096;
    if (j < n - 1)
      asm volatile("s_waitcnt vmcnt(6)" ::: "memory");
    else
      asm volatile("s_waitcnt vmcnt(0)" ::: "memory");
    __builtin_amdgcn_s_barrier();
    __builtin_amdgcn_sched_barrier(0);
    mfma_tile(Ac, Bc, acc, rl0, hh, e7, jj);
    __builtin_amdgcn_sched_barrier(0);
    __builtin_amdgcn_s_barrier();
    if (j + 2 < n)
      issue_tile((j + 2) * 64, A0, A1, kSplit, sA, K, Wt, m0, wrow, rq, kqs, lo,
                 Ac, Bc);
  }

  // C/D layout: col = lane&15, row = (lane>>4)*4 + reg  [m89-verified]
  const int rb = m0 + w * 32 + (hh << 2);
  if (MODE <= MODE_L) {
    float add0 = 0.f, add1 = 0.f, add2 = 0.f, add3 = 0.f;
    if (MODE == MODE_L) {
      add0 = biasP[bn * 64 + jj];
      add1 = biasP[bn * 64 + 16 + jj];
      add2 = biasP[bn * 64 + 32 + jj];
      add3 = biasP[bn * 64 + 48 + jj];
    }
    const int j = bn * 16 + jj;  // hidden unit
#pragma unroll
    for (int m = 0; m < 2; ++m) {
#pragma unroll
      for (int r = 0; r < 4; ++r) {
        int b = rb + m * 16 + r;
        float g0v, g1v, g2v, g3v;
        if (MODE == MODE_L0) {
          const u16* G = Gfull + (size_t)b * 4096 + bn * 64 + jj;
          g0v = acc[m][0][r] + bf2f(G[0]);
          g1v = acc[m][1][r] + bf2f(G[16]);
          g2v = acc[m][2][r] + bf2f(G[32]);
          g3v = acc[m][3][r] + bf2f(G[48]);
        } else {
          g0v = acc[m][0][r] + add0;
          g1v = acc[m][1][r] + add1;
          g2v = acc[m][2][r] + add2;
          g3v = acc[m][3][r] + add3;
        }
        float iv = sigm(g0v), fv = sigm(g1v), gv = tanhfast(g2v), ov = sigm(g3v);
        size_t ci = (size_t)b * 1024 + j;
        float cn = fv * Cst[ci] + iv * gv;
        Cst[ci] = cn;
        Hout[ci] = f2bf(ov * tanhfast(cn));
      }
    }
  } else if (MODE == MODE_FC) {
#pragma unroll
    for (int g = 0; g < 4; ++g) {
      int nn = bn * 64 + g * 16 + jj;
      if (nn < 204) {
        float bv2 = biasP[nn];
#pragma unroll
        for (int m = 0; m < 2; ++m)
#pragma unroll
          for (int r = 0; r < 4; ++r) {
            int b = rb + m * 16 + r;
            outp[((size_t)b * 128 + t) * 204 + nn] = acc[m][g][r] + bv2;
          }
      }
    }
  } else if (MODE == MODE_G0) {
#pragma unroll
    for (int g = 0; g < 4; ++g) {
      int P = bn * 64 + g * 16 + jj;
      float bv2 = biasP[P];
#pragma unroll
      for (int m = 0; m < 2; ++m)
#pragma unroll
        for (int r = 0; r < 4; ++r) {
          int b = rb + m * 16 + r;
          Hout[(size_t)b * 4096 + P] = f2bf(acc[m][g][r] + bv2);
        }
    }
  } else {  // MODE_H / MODE_C : init states, cols are orig n = lay*1024 + j
#pragma unroll
    for (int g = 0; g < 4; ++g) {
      int nn = bn * 64 + g * 16 + jj;
      int lay = nn >> 10, j2 = nn & 1023;
      float bv2 = biasP[nn];
#pragma unroll
      for (int m = 0; m < 2; ++m)
#pragma unroll
        for (int r = 0; r < 4; ++r) {
          int b = rb + m * 16 + r;
          float v = acc[m][g][r] + bv2;
          if (MODE == MODE_H)
            Hout[(size_t)((lay * 2 + 1) * 256 + b) * 1024 + j2] = f2bf(v);
          else
            outp[(size_t)(lay * 256 + b) * 1024 + j2] = v;
        }
    }
  }
}

// Grid barrier: release fence (writeback dirty h/c lines to MALL, NO
// invalidate -> weights stay cached) + two-level counter/flag. NO acquire
// fence: consumers read h via coherent (L2-bypass) loads instead.
DEVINL void grid_barrier(u32* bar, int bid, int ep) {
  __syncthreads();  // drains each wave's stores before s_barrier
  if (threadIdx.x == 0) {
    __builtin_amdgcn_fence(__ATOMIC_RELEASE, "agent");  // wb dirty lines
    __hip_atomic_fetch_add(bar + (bid & 7) * 64, 1u, __ATOMIC_RELAXED,
                           __HIP_MEMORY_SCOPE_AGENT);
    if (bid == 0) {
#pragma unroll 1
      for (int g = 0; g < 8; ++g)
        while (__hip_atomic_load(bar + g * 64, __ATOMIC_RELAXED,
                                 __HIP_MEMORY_SCOPE_AGENT) < (u32)ep * 49u)
          __builtin_amdgcn_s_sleep(8);
      __hip_atomic_store(bar + 512, (u32)ep, __ATOMIC_RELAXED,
                         __HIP_MEMORY_SCOPE_AGENT);
    } else {
#pragma unroll 1
      while (__hip_atomic_load(bar + 512, __ATOMIC_RELAXED,
                               __HIP_MEMORY_SCOPE_AGENT) < (u32)ep)
        __builtin_amdgcn_s_sleep(8);
    }
  }
  __syncthreads();
}

// Persistent pipelined kernel, PLAIN launch; 392 blocks co-resident:
// LDS 48KB -> 3 blocks/CU; launch_bounds(256,2) -> VGPR<=128 -> >=2/CU;
// 392 <= 512. bid&7 ~ XCD affinity (bn>>3 == bid&7) and barrier group.
__global__ __launch_bounds__(256, 2) void persist_kernel(Params p, u32* bar) {
  __shared__ u16 Al[2 * 128 * 64];  // 32KB
  __shared__ u16 Bl[2 * 64 * 64];   // 16KB
  const int bid = blockIdx.x;
  int job, mb, bn;
  if (bid < 384) {
    job = bid >> 7;
    int r = bid & 127;
    bn = (r & 7) * 8 + (r >> 4);
    mb = (r >> 3) & 1;
  } else {
    job = 3;
    int r = bid - 384;
    mb = r >> 2;
    bn = r & 3;
  }
  u16* HB = p.HB;
#define HBP(lay, pp) (HB + (size_t)(((lay)*2 + (pp)) * 256) * 1024)
  for (int i = 0; i <= 130; ++i) {
    int t = i - job;
    if ((unsigned)t < 128u) {
      int par = t & 1, pv = par ^ 1;
      if (job == 0) {
        mm_body<MODE_L0>(Al, Bl, HBP(0, pv), nullptr, 1024, 1 << 30, 1024,
                         p.WT0, mb * 128, bn, t, p.G0P, nullptr, p.CC,
                         HBP(0, par), nullptr);
      } else if (job == 1) {
        mm_body<MODE_L>(Al, Bl, HBP(0, par), HBP(1, pv), 1024, 1024, 2048,
                        p.WT1, mb * 128, bn, t, nullptr, p.B1P,
                        p.CC + (size_t)256 * 1024, HBP(1, par), nullptr);
      } else if (job == 2) {
        mm_body<MODE_L>(Al, Bl, HBP(1, par), HBP(2, pv), 1024, 1024, 2048,
                        p.WT2, mb * 128, bn, t, nullptr, p.B2P,
                        p.CC + (size_t)512 * 1024, HBP(2, par), nullptr);
      } else {
        mm_body<MODE_FC>(Al, Bl, HBP(2, par), nullptr, 1024, 1 << 30, 1024,
                         p.FCW, mb * 128, bn, t, nullptr, p.fc_b, nullptr,
                         nullptr, p.out);
      }
    }
    if (i < 130) grid_barrier(bar, bid, i + 1);
  }
#undef HBP
}

// one-time: G0 = x_in@W_ih0+biases (permuted), h/c init = frame@in{h,c}_W + b
__global__ __launch_bounds__(256, 2) void setup_mm(Params p) {
  __shared__ u16 Al[2 * 128 * 64];
  __shared__ u16 Bl[2 * 64 * 64];
  int bid = blockIdx.x;
  if (bid < 128) {
    mm_body<MODE_G0>(Al, Bl, p.FRB, nullptr, 256, 1 << 30, 256, p.WT00,
                     (bid >> 6) * 128, bid & 63, 0, nullptr, p.G0B, nullptr,
                     p.G0P, nullptr);
  } else if (bid < 224) {
    int b2 = bid - 128;
    mm_body<MODE_H>(Al, Bl, p.FRB, nullptr, 256, 1 << 30, 256, p.WIH,
                    (b2 / 48) * 128, b2 % 48, 0, nullptr, p.inh_b, nullptr,
                    p.HB, nullptr);
  } else {
    int b2 = bid - 224;
    mm_body<MODE_C>(Al, Bl, p.FRB, nullptr, 256, 1 << 30, 256, p.WIC,
                    (b2 / 48) * 128, b2 % 48, 0, nullptr, p.inc_b, nullptr,
                    nullptr, p.CC);
  }
}

// fp32 [K][N] sources -> bf16 transposed dst [Nout][Ktot] (K contiguous),
// optional gate permutation of output cols, zero pad k>=Kvalid / n>=Nvalid.
__global__ __launch_bounds__(256) void transpose_bf16(
    const float* __restrict__ srcA, const float* __restrict__ srcB,
    int srcStride, int kSplit, int Kvalid, int Nvalid, int perm,
    u16* __restrict__ dst, int Ktot) {
  __shared__ float tile[64][17];
  int P0 = blockIdx.x * 16;
  int k0 = blockIdx.y * 64;
  int t = threadIdx.x;
  int nl = t & 15;
  int kh = t >> 4;
  int P = P0 + nl;
  int n = perm ? permcol(P) : P;
  bool nok = (n < Nvalid);
#pragma unroll
  for (int q = 0; q < 4; ++q) {
    int kl = q * 16 + kh;
    int k = k0 + kl;
    float v = 0.f;
    if (nok && k < Kvalid) {
      const float* s = (k < kSplit) ? (srcA + (size_t)k * srcStride)
                                    : (srcB + (size_t)(k - kSplit) * srcStride);
      v = s[n];
    }
    tile[kl][nl] = v;
  }
  __syncthreads();
  int jo = t >> 4;
  int kb = (t & 15) << 2;
  unsigned long long pk =
      (unsigned long long)f2bf(tile[kb + 0][jo]) |
      ((unsigned long long)f2bf(tile[kb + 1][jo]) << 16) |
      ((unsigned long long)f2bf(tile[kb + 2][jo]) << 32) |
      ((unsigned long long)f2bf(tile[kb + 3][jo]) << 48);
  *(unsigned long long*)(dst + (size_t)(P0 + jo) * Ktot + k0 + kb) = pk;
}

__global__ __launch_bounds__(256) void build_frame(const float* __restrict__ inputs,
                                                   u16* __restrict__ FRB) {
  int id = blockIdx.x * 256 + threadIdx.x;  // 256*256
  int b = id >> 8, k = id & 255;
  FRB[id] = (k < 204) ? f2bf(inputs[b * 204 + k]) : (u16)0;
}

// G0 bias incl. one-hot label row; layer1/2 combined biases (permuted cols)
__global__ __launch_bounds__(256) void build_bias(
    const float* __restrict__ W_ih0, const float* __restrict__ b_ih0,
    const float* __restrict__ b_hh0, const float* __restrict__ b_ih1,
    const float* __restrict__ b_hh1, const float* __restrict__ b_ih2,
    const float* __restrict__ b_hh2, const int* __restrict__ labels,
    float* __restrict__ G0B, float* __restrict__ B1P, float* __restrict__ B2P) {
  int P = blockIdx.x * 256 + threadIdx.x;  // 4096
  int n = permcol(P);
  int lab = labels[0];
  G0B[P] = W_ih0[(size_t)(204 + lab) * 4096 + n] + b_ih0[n] + b_hh0[n];
  B1P[P] = b_ih1[n] + b_hh1[n];
  B2P[P] = b_ih2[n] + b_hh2[n];
}

extern "C" void kernel_launch(void* const* d_in, const int* in_sizes, int n_in,
                              void* d_out, int out_size, void* d_ws,
                              size_t ws_size, hipStream_t stream) {
  const float* inputs = (const float*)d_in[0];
  const float* W_ih0 = (const float*)d_in[1];
  const float* W_hh0 = (const float*)d_in[2];
  const float* b_ih0 = (const float*)d_in[3];
  const float* b_hh0 = (const float*)d_in[4];
  const float* W_ih1 = (const float*)d_in[5];
  const float* W_hh1 = (const float*)d_in[6];
  const float* b_ih1 = (const float*)d_in[7];
  const float* b_hh1 = (const float*)d_in[8];
  const float* W_ih2 = (const float*)d_in[9];
  const float* W_hh2 = (const float*)d_in[10];
  const float* b_ih2 = (const float*)d_in[11];
  const float* b_hh2 = (const float*)d_in[12];
  const float* fc_W = (const float*)d_in[13];
  const float* fc_b = (const float*)d_in[14];
  const float* inh_W = (const float*)d_in[15];
  const float* inh_b = (const float*)d_in[16];
  const float* inc_W = (const float*)d_in[17];
  const float* inc_b = (const float*)d_in[18];
  const int* labels = (const int*)d_in[19];

  char* ws = (char*)d_ws;
  size_t off = 0;
  auto alloc = [&](size_t bytes) {
    void* r = ws + off;
    off = (off + bytes + 255) & ~(size_t)255;
    return r;
  };
  u16* WT0 = (u16*)alloc(4096ull * 1024 * 2);
  u16* WT1 = (u16*)alloc(4096ull * 2048 * 2);
  u16* WT2 = (u16*)alloc(4096ull * 2048 * 2);
  u16* WT00 = (u16*)alloc(4096ull * 256 * 2);
  u16* FCW = (u16*)alloc(256ull * 1024 * 2);
  u16* WIH = (u16*)alloc(3072ull * 256 * 2);
  u16* WIC = (u16*)alloc(3072ull * 256 * 2);
  u16* FRB = (u16*)alloc(256ull * 256 * 2);
  u16* HB = (u16*)alloc(3ull * 2 * 256 * 1024 * 2);
  u16* G0P = (u16*)alloc(256ull * 4096 * 2);
  float* G0B = (float*)alloc(4096ull * 4);
  float* B1P = (float*)alloc(4096ull * 4);
  float* B2P = (float*)alloc(4096ull * 4);
  float* CC = (float*)alloc(3ull * 256 * 1024 * 4);
  u32* BAR = (u32*)alloc(4096);  // 8 group counters (64-u32 apart) + flag @512
  if (off > ws_size) return;  // workspace too small: fail loudly (validation)

  const int BIG = 1 << 30;
  // weight repack (one-time per call)
  transpose_bf16<<<dim3(256, 16), 256, 0, stream>>>(W_hh0, nullptr, 4096, BIG, 1024, 4096, 1, WT0, 1024);
  transpose_bf16<<<dim3(256, 32), 256, 0, stream>>>(W_ih1, W_hh1, 4096, 1024, 2048, 4096, 1, WT1, 2048);
  transpose_bf16<<<dim3(256, 32), 256, 0, stream>>>(W_ih2, W_hh2, 4096, 1024, 2048, 4096, 1, WT2, 2048);
  transpose_bf16<<<dim3(256, 4), 256, 0, stream>>>(W_ih0, nullptr, 4096, BIG, 204, 4096, 1, WT00, 256);
  transpose_bf16<<<dim3(16, 16), 256, 0, stream>>>(fc_W, nullptr, 204, BIG, 1024, 204, 0, FCW, 1024);
  transpose_bf16<<<dim3(192, 4), 256, 0, stream>>>(inh_W, nullptr, 3072, BIG, 204, 3072, 0, WIH, 256);
  transpose_bf16<<<dim3(192, 4), 256, 0, stream>>>(inc_W, nullptr, 3072, BIG, 204, 3072, 0, WIC, 256);
  build_frame<<<256, 256, 0, stream>>>(inputs, FRB);
  build_bias<<<16, 256, 0, stream>>>(W_ih0, b_ih0, b_hh0, b_ih1, b_hh1, b_ih2,
                                     b_hh2, labels, G0B, B1P, B2P);
  hipMemsetAsync(BAR, 0, 4096, stream);

  Params p;
  p.fc_b = fc_b; p.inh_b = inh_b; p.inc_b = inc_b;
  p.WT0 = WT0; p.WT1 = WT1; p.WT2 = WT2; p.WT00 = WT00; p.FCW = FCW;
  p.WIH = WIH; p.WIC = WIC; p.FRB = FRB; p.HB = HB;
  p.G0P = G0P; p.G0B = G0B; p.B1P = B1P; p.B2P = B2P; p.CC = CC;
  p.out = (float*)d_out;

  setup_mm<<<320, 256, 0, stream>>>(p);

  // persistent pipelined sequence: one plain launch, software grid barrier
  persist_kernel<<<392, 256, 0, stream>>>(p, BAR);
}